// Round 1
// baseline (206.776 us; speedup 1.0000x reference)
//
#include <hip/hip_runtime.h>

// Problem constants (fixed by the reference setup_inputs()).
#define BB 8
#define CC 256
#define EE 18000
#define TT 4500

// ---- tiny setup kernels: per-(b,g) counts -> reciprocal ----

__global__ void zero_counts_kernel(int* __restrict__ counts) {
    int i = blockIdx.x * blockDim.x + threadIdx.x;
    if (i < BB * TT) counts[i] = 0;
}

__global__ void count_kernel(const int* __restrict__ gid, int* __restrict__ counts) {
    int i = blockIdx.x * blockDim.x + threadIdx.x;
    if (i < BB * EE) {
        int b = i / EE;
        int g = gid[i];
        atomicAdd(&counts[b * TT + g], 1);
    }
}

__global__ void inv_kernel(const int* __restrict__ counts, float* __restrict__ inv) {
    int i = blockIdx.x * blockDim.x + threadIdx.x;
    if (i < BB * TT) {
        int c = counts[i];
        inv[i] = 1.0f / (float)(c > 0 ? c : 1);
    }
}

// ---- main kernel: one block per (b, c) row; bins in LDS ----
// fe row read coalesced as float4; group ids (shared across the 256 blocks
// of a batch) are L2-resident; LDS atomics accumulate into 4500 bins;
// coalesced epilogue writes out[b, c, :] = bins * inv_count.

__global__ __launch_bounds__(256) void pool_kernel(const float* __restrict__ fe,
                                                   const int* __restrict__ gid,
                                                   const float* __restrict__ inv,
                                                   float* __restrict__ out) {
    __shared__ float bins[TT];   // 18000 B -> 8 blocks/CU
    const int b   = blockIdx.x / CC;
    const int c   = blockIdx.x % CC;
    const int tid = threadIdx.x;

    for (int t = tid; t < TT; t += 256) bins[t] = 0.0f;
    __syncthreads();

    const float4* fe4  = reinterpret_cast<const float4*>(fe + (size_t)(b * CC + c) * EE);
    const int4*   gid4 = reinterpret_cast<const int4*>(gid + (size_t)b * EE);

    // EE/4 = 4500 float4 elements per row
    for (int i = tid; i < EE / 4; i += 256) {
        float4 v = fe4[i];
        int4   g = gid4[i];
        atomicAdd(&bins[g.x], v.x);
        atomicAdd(&bins[g.y], v.y);
        atomicAdd(&bins[g.z], v.z);
        atomicAdd(&bins[g.w], v.w);
    }
    __syncthreads();

    const float* invb = inv + b * TT;
    float*       outb = out + (size_t)(b * CC + c) * TT;
    for (int t = tid; t < TT; t += 256) outb[t] = bins[t] * invb[t];
}

extern "C" void kernel_launch(void* const* d_in, const int* in_sizes, int n_in,
                              void* d_out, int out_size, void* d_ws, size_t ws_size,
                              hipStream_t stream) {
    const float* fe  = (const float*)d_in[0];
    const int*   gid = (const int*)d_in[1];
    float*       out = (float*)d_out;

    // workspace: [0, B*T) ints = counts ; [B*T, 2*B*T) floats = inv counts
    int*   counts = (int*)d_ws;
    float* inv    = (float*)d_ws + (size_t)BB * TT;

    const int NBT = BB * TT;   // 36000
    const int NBE = BB * EE;   // 144000

    zero_counts_kernel<<<(NBT + 255) / 256, 256, 0, stream>>>(counts);
    count_kernel<<<(NBE + 255) / 256, 256, 0, stream>>>(gid, counts);
    inv_kernel<<<(NBT + 255) / 256, 256, 0, stream>>>(counts, inv);
    pool_kernel<<<BB * CC, 256, 0, stream>>>(fe, gid, inv, out);
}